// Round 3
// baseline (570.350 us; speedup 1.0000x reference)
//
#include <hip/hip_runtime.h>
#include <math.h>

constexpr int NN   = 100000;
constexpr int NE   = 1600000;
constexpr int FIN  = 256;
constexpr int HID  = 64;
constexpr int FOUT = 40;
constexpr float SLOPE = 0.2f;
constexpr int NB   = (NN + 255) / 256;   // 391 blocks for node-wise scans

// ---------------- GEMM1: z = feat @ W1, fused el/er + dst histogram --------
// 64-node x 64-col tile, K=256 in 4 slices of 64. 256 thr, 4x4 per thread.
// Histogram of dst is fused in (fire-and-forget atomics overlap the FMA loop).
__global__ __launch_bounds__(256) void gemm1_kernel(
    const float* __restrict__ feat, const float* __restrict__ W1,
    const float* __restrict__ al, const float* __restrict__ ar,
    const int* __restrict__ dst, int* __restrict__ deg,
    float* __restrict__ z, float* __restrict__ el, float* __restrict__ er)
{
    // fused histogram: 1563 blocks * 256 thr * 4 edges = 1600512 >= NE
    {
        int base = (blockIdx.x * 256 + threadIdx.x) * 4;
        if (base < NE) {  // NE % 4 == 0 so base+3 < NE
            const int4 d4 = *(const int4*)&dst[base];
            atomicAdd(&deg[d4.x], 1); atomicAdd(&deg[d4.y], 1);
            atomicAdd(&deg[d4.z], 1); atomicAdd(&deg[d4.w], 1);
        }
    }

    __shared__ float sT[64 * 65];   // A^T: [k][m], stride 65 (conflict-free)
    __shared__ float sB[64 * 64];   // B:   [k][c]
    const int t  = threadIdx.x;
    const int tm = t >> 4;
    const int tc = t & 15;
    const int ntile = blockIdx.x * 64;

    float acc[4][4] = {};

    for (int kt = 0; kt < 4; ++kt) {
        #pragma unroll
        for (int i = 0; i < 4; ++i) {
            int nloc = tm + 16 * i;
            int n = ntile + nloc; if (n >= NN) n = NN - 1;
            float4 f = *(const float4*)&feat[(size_t)n * FIN + kt * 64 + tc * 4];
            int kk = tc * 4;
            sT[(kk + 0) * 65 + nloc] = f.x;
            sT[(kk + 1) * 65 + nloc] = f.y;
            sT[(kk + 2) * 65 + nloc] = f.z;
            sT[(kk + 3) * 65 + nloc] = f.w;
        }
        #pragma unroll
        for (int i = 0; i < 4; ++i) {
            int vec = t + 256 * i;
            *(float4*)&sB[vec * 4] = *(const float4*)&W1[kt * 4096 + vec * 4];
        }
        __syncthreads();
        #pragma unroll 8
        for (int k = 0; k < 64; ++k) {
            float a0 = sT[k * 65 + 4 * tm + 0];
            float a1 = sT[k * 65 + 4 * tm + 1];
            float a2 = sT[k * 65 + 4 * tm + 2];
            float a3 = sT[k * 65 + 4 * tm + 3];
            float4 b = *(const float4*)&sB[k * 64 + 4 * tc];
            acc[0][0] += a0 * b.x; acc[0][1] += a0 * b.y; acc[0][2] += a0 * b.z; acc[0][3] += a0 * b.w;
            acc[1][0] += a1 * b.x; acc[1][1] += a1 * b.y; acc[1][2] += a1 * b.z; acc[1][3] += a1 * b.w;
            acc[2][0] += a2 * b.x; acc[2][1] += a2 * b.y; acc[2][2] += a2 * b.z; acc[2][3] += a2 * b.w;
            acc[3][0] += a3 * b.x; acc[3][1] += a3 * b.y; acc[3][2] += a3 * b.z; acc[3][3] += a3 * b.w;
        }
        __syncthreads();
    }

    float alv[4], arv[4];
    #pragma unroll
    for (int j = 0; j < 4; ++j) { alv[j] = al[4 * tc + j]; arv[j] = ar[4 * tc + j]; }

    #pragma unroll
    for (int i = 0; i < 4; ++i) {
        int n = ntile + 4 * tm + i;
        float pl = acc[i][0] * alv[0] + acc[i][1] * alv[1] + acc[i][2] * alv[2] + acc[i][3] * alv[3];
        float pr = acc[i][0] * arv[0] + acc[i][1] * arv[1] + acc[i][2] * arv[2] + acc[i][3] * arv[3];
        #pragma unroll
        for (int off = 8; off >= 1; off >>= 1) {
            pl += __shfl_xor(pl, off);
            pr += __shfl_xor(pr, off);
        }
        if (n < NN) {
            float4 zv = make_float4(acc[i][0], acc[i][1], acc[i][2], acc[i][3]);
            *(float4*)&z[(size_t)n * HID + 4 * tc] = zv;
            if (tc == 0) { el[n] = pl; er[n] = pr; }
        }
    }
}

// ---------------- GEMM2: z2 = h @ W2, fused el2/er2 ------------------------
__global__ __launch_bounds__(256) void gemm2_kernel(
    const float* __restrict__ h, const float* __restrict__ W2,
    const float* __restrict__ al, const float* __restrict__ ar,
    float* __restrict__ z2, float* __restrict__ el, float* __restrict__ er)
{
    __shared__ float sh[4][64];
    const int w = threadIdx.x >> 6, lane = threadIdx.x & 63;
    const int n = blockIdx.x * 4 + w;          // NN % 4 == 0
    sh[w][lane] = h[(size_t)n * HID + lane];
    __syncthreads();
    float acc = 0.f;
    if (lane < FOUT) {
        #pragma unroll 8
        for (int k = 0; k < 64; ++k) acc += sh[w][k] * W2[k * FOUT + lane];
    }
    float pl = (lane < FOUT) ? acc * al[lane] : 0.f;
    float pr = (lane < FOUT) ? acc * ar[lane] : 0.f;
    #pragma unroll
    for (int off = 32; off >= 1; off >>= 1) { pl += __shfl_xor(pl, off); pr += __shfl_xor(pr, off); }
    if (lane == 0) { el[n] = pl; er[n] = pr; }
    if (lane < FOUT) z2[(size_t)n * FOUT + lane] = acc;
}

// ---------------- CSR build: scans + scatter --------------------------------
__global__ __launch_bounds__(256) void scan_reduce_kernel(
    const int* __restrict__ deg, int* __restrict__ bsum)
{
    __shared__ int tmp[256];
    int idx = blockIdx.x * 256 + threadIdx.x;
    int v = (idx < NN) ? deg[idx] : 0;
    tmp[threadIdx.x] = v; __syncthreads();
    for (int off = 128; off >= 1; off >>= 1) {
        if (threadIdx.x < off) tmp[threadIdx.x] += tmp[threadIdx.x + off];
        __syncthreads();
    }
    if (threadIdx.x == 0) bsum[blockIdx.x] = tmp[0];
}

__global__ __launch_bounds__(512) void scan_top_kernel(
    const int* __restrict__ bsum, int* __restrict__ bofs, int* __restrict__ row_ptr)
{
    __shared__ int tmp[512];
    int t = threadIdx.x;
    int v = (t < NB) ? bsum[t] : 0;
    tmp[t] = v; __syncthreads();
    for (int off = 1; off < 512; off <<= 1) {
        int x = (t >= off) ? tmp[t - off] : 0;
        __syncthreads();
        tmp[t] += x;
        __syncthreads();
    }
    int excl = tmp[t] - v;
    if (t < NB) bofs[t] = excl;
    if (t == NB - 1) row_ptr[NN] = excl + v;  // total = NE
}

// writes row_ptr AND cnt (= running cursor for scatter)
__global__ __launch_bounds__(256) void scan_final_kernel(
    const int* __restrict__ deg, const int* __restrict__ bofs,
    int* __restrict__ row_ptr, int* __restrict__ cnt)
{
    __shared__ int tmp[256];
    int t = threadIdx.x;
    int idx = blockIdx.x * 256 + t;
    int v = (idx < NN) ? deg[idx] : 0;
    tmp[t] = v; __syncthreads();
    for (int off = 1; off < 256; off <<= 1) {
        int x = (t >= off) ? tmp[t - off] : 0;
        __syncthreads();
        tmp[t] += x;
        __syncthreads();
    }
    if (idx < NN) {
        int excl = bofs[blockIdx.x] + tmp[t] - v;
        row_ptr[idx] = excl;
        cnt[idx] = excl;
    }
}

// 4 edges per thread: 4 independent atomic->store chains for MLP
__global__ __launch_bounds__(256) void scatter_kernel(
    const int* __restrict__ src, const int* __restrict__ dst,
    int* __restrict__ cnt, int* __restrict__ esrc)
{
    int base = (blockIdx.x * 256 + threadIdx.x) * 4;
    if (base >= NE) return;   // NE % 4 == 0
    const int4 s4 = *(const int4*)&src[base];
    const int4 d4 = *(const int4*)&dst[base];
    int p0 = atomicAdd(&cnt[d4.x], 1);
    int p1 = atomicAdd(&cnt[d4.y], 1);
    int p2 = atomicAdd(&cnt[d4.z], 1);
    int p3 = atomicAdd(&cnt[d4.w], 1);
    esrc[p0] = s4.x; esrc[p1] = s4.y; esrc[p2] = s4.z; esrc[p3] = s4.w;
}

// ---------------- fused per-destination GAT gather -------------------------
// One wave per destination node. Fast path (deg <= 64, always true here):
// logits live in registers, single LDS staging, no recompute.
template<int F, bool FINAL_LAYER>
__global__ __launch_bounds__(256) void gat_gather_kernel(
    const int* __restrict__ row_ptr, const int* __restrict__ esrc,
    const float* __restrict__ el, const float* __restrict__ er,
    const float* __restrict__ z, const float* __restrict__ bias,
    float* __restrict__ out)
{
    __shared__ float sw[4][64];
    __shared__ int   ssn[4][64];
    const int w = threadIdx.x >> 6, lane = threadIdx.x & 63;
    const int d = blockIdx.x * 4 + w;          // NN % 4 == 0
    const int r0 = row_ptr[d], r1 = row_ptr[d + 1];
    const int cnt = r1 - r0;
    const float erd = er[d];

    float accv = 0.f;
    float s = 0.f;

    if (cnt <= 64) {
        // ---- fast path: whole row in one wave-chunk ----
        int sn = 0; float v = -INFINITY;
        if (lane < cnt) {
            sn = esrc[r0 + lane];
            v = el[sn] + erd;
            v = (v >= 0.f) ? v : SLOPE * v;
        }
        float m = v;
        #pragma unroll
        for (int off = 32; off >= 1; off >>= 1) m = fmaxf(m, __shfl_xor(m, off));
        float wv = (lane < cnt) ? __expf(v - m) : 0.f;
        s = wv;
        #pragma unroll
        for (int off = 32; off >= 1; off >>= 1) s += __shfl_xor(s, off);
        sw[w][lane] = wv; ssn[w][lane] = sn;   // wave-synchronous, no barrier
        if (lane < F) {
            int j = 0;
            for (; j + 4 <= cnt; j += 4) {
                float w0 = sw[w][j],     w1 = sw[w][j + 1];
                float w2 = sw[w][j + 2], w3 = sw[w][j + 3];
                int   s0 = ssn[w][j],     s1 = ssn[w][j + 1];
                int   s2 = ssn[w][j + 2], s3 = ssn[w][j + 3];
                accv += w0 * z[(size_t)s0 * F + lane];
                accv += w1 * z[(size_t)s1 * F + lane];
                accv += w2 * z[(size_t)s2 * F + lane];
                accv += w3 * z[(size_t)s3 * F + lane];
            }
            for (; j < cnt; ++j)
                accv += sw[w][j] * z[(size_t)ssn[w][j] * F + lane];
        }
    } else {
        // ---- generic fallback (deg > 64) ----
        float m = -INFINITY;
        for (int e = r0 + lane; e < r1; e += 64) {
            float v = el[esrc[e]] + erd;
            v = (v >= 0.f) ? v : SLOPE * v;
            m = fmaxf(m, v);
        }
        #pragma unroll
        for (int off = 32; off >= 1; off >>= 1) m = fmaxf(m, __shfl_xor(m, off));
        for (int base = r0; base < r1; base += 64) {
            int e = base + lane;
            float wv = 0.f; int sn = 0;
            if (e < r1) {
                sn = esrc[e];
                float v = el[sn] + erd;
                v = (v >= 0.f) ? v : SLOPE * v;
                wv = __expf(v - m);
            }
            sw[w][lane] = wv; ssn[w][lane] = sn;
            s += wv;
            int c = r1 - base; if (c > 64) c = 64;
            if (lane < F) {
                for (int j = 0; j < c; ++j)
                    accv += sw[w][j] * z[(size_t)ssn[w][j] * F + lane];
            }
        }
        #pragma unroll
        for (int off = 32; off >= 1; off >>= 1) s += __shfl_xor(s, off);
    }

    float res = (cnt > 0) ? (accv / s) : 0.f;

    if (!FINAL_LAYER) {
        if (lane < F) {
            float v = res + bias[lane];
            out[(size_t)d * F + lane] = (v > 0.f) ? v : 0.f;
        }
    } else {
        float v = (lane < F) ? res + bias[lane] : -INFINITY;
        float mx = v;
        #pragma unroll
        for (int off = 32; off >= 1; off >>= 1) mx = fmaxf(mx, __shfl_xor(mx, off));
        float ex = (lane < F) ? __expf(v - mx) : 0.f;
        float sm = ex;
        #pragma unroll
        for (int off = 32; off >= 1; off >>= 1) sm += __shfl_xor(sm, off);
        if (lane < F) out[(size_t)d * F + lane] = v - mx - __logf(sm);
    }
}

extern "C" void kernel_launch(void* const* d_in, const int* in_sizes, int n_in,
                              void* d_out, int out_size, void* d_ws, size_t ws_size,
                              hipStream_t stream) {
    const float* feat = (const float*)d_in[0];
    const int*   src  = (const int*)d_in[1];
    const int*   dst  = (const int*)d_in[2];
    const float* W1   = (const float*)d_in[3];
    const float* b1   = (const float*)d_in[4];
    const float* al1  = (const float*)d_in[5];
    const float* ar1  = (const float*)d_in[6];
    const float* W2   = (const float*)d_in[7];
    const float* b2   = (const float*)d_in[8];
    const float* al2  = (const float*)d_in[9];
    const float* ar2  = (const float*)d_in[10];
    float* out = (float*)d_out;

    float* ws    = (float*)d_ws;
    float* z1    = ws;                          // NN*64 (reused for z2)
    float* h     = z1 + (size_t)NN * HID;       // NN*64
    float* el1   = h + (size_t)NN * HID;
    float* er1   = el1 + NN;
    float* el2   = er1 + NN;
    float* er2   = el2 + NN;
    int*   deg   = (int*)(er2 + NN);            // NN
    int*   cnt   = deg + NN;                    // NN
    int*   rowp  = cnt + NN;                    // NN+1
    int*   bsum  = rowp + NN + 1;               // NB
    int*   bofs  = bsum + NB;                   // NB
    int*   esrc  = bofs + NB;                   // NE
    float* z2    = z1;

    hipMemsetAsync(deg, 0, NN * sizeof(int), stream);

    // ---- layer-1 GEMM with fused dst-histogram ----
    gemm1_kernel<<<(NN + 63) / 64, 256, 0, stream>>>(feat, W1, al1, ar1, dst, deg, z1, el1, er1);

    // ---- CSR build ----
    scan_reduce_kernel<<<NB, 256, 0, stream>>>(deg, bsum);
    scan_top_kernel<<<1, 512, 0, stream>>>(bsum, bofs, rowp);
    scan_final_kernel<<<NB, 256, 0, stream>>>(deg, bofs, rowp, cnt);
    scatter_kernel<<<(NE / 4 + 255) / 256, 256, 0, stream>>>(src, dst, cnt, esrc);

    // ---- layer 1 gather ----
    gat_gather_kernel<HID, false><<<NN / 4, 256, 0, stream>>>(rowp, esrc, el1, er1, z1, b1, h);

    // ---- layer 2 ----
    gemm2_kernel<<<NN / 4, 256, 0, stream>>>(h, W2, al2, ar2, z2, el2, er2);
    gat_gather_kernel<FOUT, true><<<NN / 4, 256, 0, stream>>>(rowp, esrc, el2, er2, z2, b2, out);
}

// Round 4
// 479.692 us; speedup vs baseline: 1.1890x; 1.1890x over previous
//
#include <hip/hip_runtime.h>
#include <math.h>

constexpr int NN   = 100000;
constexpr int NE   = 1600000;
constexpr int FIN  = 256;
constexpr int HID  = 64;
constexpr int FOUT = 40;
constexpr float SLOPE = 0.2f;
constexpr int NB    = (NN + 255) / 256;   // 391 node-scan blocks == bucket count
constexpr int NBUCK = NB;                 // bucket = dst >> 8 (256 nodes/bucket)
constexpr int TILE_A = 8192;              // edges per partition-A workgroup
constexpr int NWG_A = (NE + TILE_A - 1) / TILE_A;  // 196

// ---------------- GEMM1: z = feat @ W1, fused el/er + dst histogram --------
__global__ __launch_bounds__(256) void gemm1_kernel(
    const float* __restrict__ feat, const float* __restrict__ W1,
    const float* __restrict__ al, const float* __restrict__ ar,
    const int* __restrict__ dst, int* __restrict__ deg,
    float* __restrict__ z, float* __restrict__ el, float* __restrict__ er)
{
    // fused histogram: 1563 blocks * 256 thr * 4 edges >= NE
    {
        int base = (blockIdx.x * 256 + threadIdx.x) * 4;
        if (base < NE) {  // NE % 4 == 0
            const int4 d4 = *(const int4*)&dst[base];
            atomicAdd(&deg[d4.x], 1); atomicAdd(&deg[d4.y], 1);
            atomicAdd(&deg[d4.z], 1); atomicAdd(&deg[d4.w], 1);
        }
    }

    __shared__ float sT[64 * 65];
    __shared__ float sB[64 * 64];
    const int t  = threadIdx.x;
    const int tm = t >> 4;
    const int tc = t & 15;
    const int ntile = blockIdx.x * 64;

    float acc[4][4] = {};

    for (int kt = 0; kt < 4; ++kt) {
        #pragma unroll
        for (int i = 0; i < 4; ++i) {
            int nloc = tm + 16 * i;
            int n = ntile + nloc; if (n >= NN) n = NN - 1;
            float4 f = *(const float4*)&feat[(size_t)n * FIN + kt * 64 + tc * 4];
            int kk = tc * 4;
            sT[(kk + 0) * 65 + nloc] = f.x;
            sT[(kk + 1) * 65 + nloc] = f.y;
            sT[(kk + 2) * 65 + nloc] = f.z;
            sT[(kk + 3) * 65 + nloc] = f.w;
        }
        #pragma unroll
        for (int i = 0; i < 4; ++i) {
            int vec = t + 256 * i;
            *(float4*)&sB[vec * 4] = *(const float4*)&W1[kt * 4096 + vec * 4];
        }
        __syncthreads();
        #pragma unroll 8
        for (int k = 0; k < 64; ++k) {
            float a0 = sT[k * 65 + 4 * tm + 0];
            float a1 = sT[k * 65 + 4 * tm + 1];
            float a2 = sT[k * 65 + 4 * tm + 2];
            float a3 = sT[k * 65 + 4 * tm + 3];
            float4 b = *(const float4*)&sB[k * 64 + 4 * tc];
            acc[0][0] += a0 * b.x; acc[0][1] += a0 * b.y; acc[0][2] += a0 * b.z; acc[0][3] += a0 * b.w;
            acc[1][0] += a1 * b.x; acc[1][1] += a1 * b.y; acc[1][2] += a1 * b.z; acc[1][3] += a1 * b.w;
            acc[2][0] += a2 * b.x; acc[2][1] += a2 * b.y; acc[2][2] += a2 * b.z; acc[2][3] += a2 * b.w;
            acc[3][0] += a3 * b.x; acc[3][1] += a3 * b.y; acc[3][2] += a3 * b.z; acc[3][3] += a3 * b.w;
        }
        __syncthreads();
    }

    float alv[4], arv[4];
    #pragma unroll
    for (int j = 0; j < 4; ++j) { alv[j] = al[4 * tc + j]; arv[j] = ar[4 * tc + j]; }

    #pragma unroll
    for (int i = 0; i < 4; ++i) {
        int n = ntile + 4 * tm + i;
        float pl = acc[i][0] * alv[0] + acc[i][1] * alv[1] + acc[i][2] * alv[2] + acc[i][3] * alv[3];
        float pr = acc[i][0] * arv[0] + acc[i][1] * arv[1] + acc[i][2] * arv[2] + acc[i][3] * arv[3];
        #pragma unroll
        for (int off = 8; off >= 1; off >>= 1) {
            pl += __shfl_xor(pl, off);
            pr += __shfl_xor(pr, off);
        }
        if (n < NN) {
            float4 zv = make_float4(acc[i][0], acc[i][1], acc[i][2], acc[i][3]);
            *(float4*)&z[(size_t)n * HID + 4 * tc] = zv;
            if (tc == 0) { el[n] = pl; er[n] = pr; }
        }
    }
}

// ---------------- GEMM2: z2 = h @ W2, fused el2/er2 ------------------------
__global__ __launch_bounds__(256) void gemm2_kernel(
    const float* __restrict__ h, const float* __restrict__ W2,
    const float* __restrict__ al, const float* __restrict__ ar,
    float* __restrict__ z2, float* __restrict__ el, float* __restrict__ er)
{
    __shared__ float sh[4][64];
    const int w = threadIdx.x >> 6, lane = threadIdx.x & 63;
    const int n = blockIdx.x * 4 + w;          // NN % 4 == 0
    sh[w][lane] = h[(size_t)n * HID + lane];
    __syncthreads();
    float acc = 0.f;
    if (lane < FOUT) {
        #pragma unroll 8
        for (int k = 0; k < 64; ++k) acc += sh[w][k] * W2[k * FOUT + lane];
    }
    float pl = (lane < FOUT) ? acc * al[lane] : 0.f;
    float pr = (lane < FOUT) ? acc * ar[lane] : 0.f;
    #pragma unroll
    for (int off = 32; off >= 1; off >>= 1) { pl += __shfl_xor(pl, off); pr += __shfl_xor(pr, off); }
    if (lane == 0) { el[n] = pl; er[n] = pr; }
    if (lane < FOUT) z2[(size_t)n * FOUT + lane] = acc;
}

// ---------------- CSR build: scans ------------------------------------------
__global__ __launch_bounds__(256) void scan_reduce_kernel(
    const int* __restrict__ deg, int* __restrict__ bsum)
{
    __shared__ int tmp[256];
    int idx = blockIdx.x * 256 + threadIdx.x;
    int v = (idx < NN) ? deg[idx] : 0;
    tmp[threadIdx.x] = v; __syncthreads();
    for (int off = 128; off >= 1; off >>= 1) {
        if (threadIdx.x < off) tmp[threadIdx.x] += tmp[threadIdx.x + off];
        __syncthreads();
    }
    if (threadIdx.x == 0) bsum[blockIdx.x] = tmp[0];
}

__global__ __launch_bounds__(512) void scan_top_kernel(
    const int* __restrict__ bsum, int* __restrict__ bofs, int* __restrict__ row_ptr)
{
    __shared__ int tmp[512];
    int t = threadIdx.x;
    int v = (t < NB) ? bsum[t] : 0;
    tmp[t] = v; __syncthreads();
    for (int off = 1; off < 512; off <<= 1) {
        int x = (t >= off) ? tmp[t - off] : 0;
        __syncthreads();
        tmp[t] += x;
        __syncthreads();
    }
    int excl = tmp[t] - v;
    if (t < NB) bofs[t] = excl;
    if (t == NB - 1) row_ptr[NN] = excl + v;  // total = NE
}

// writes row_ptr; also bucket cursor init gcur[b] = bucket base
__global__ __launch_bounds__(256) void scan_final_kernel(
    const int* __restrict__ deg, const int* __restrict__ bofs,
    int* __restrict__ row_ptr, int* __restrict__ gcur)
{
    __shared__ int tmp[256];
    int t = threadIdx.x;
    int idx = blockIdx.x * 256 + t;
    int v = (idx < NN) ? deg[idx] : 0;
    tmp[t] = v; __syncthreads();
    for (int off = 1; off < 256; off <<= 1) {
        int x = (t >= off) ? tmp[t - off] : 0;
        __syncthreads();
        tmp[t] += x;
        __syncthreads();
    }
    if (idx < NN) row_ptr[idx] = bofs[blockIdx.x] + tmp[t] - v;
    if (t == 0) gcur[blockIdx.x] = bofs[blockIdx.x];   // block b == bucket b
}

// ---------------- Pass A: bucket partition (line-dense writes) --------------
// pack = (src << 8) | (dst & 255); bucket = dst >> 8
__global__ __launch_bounds__(256) void partitionA_kernel(
    const int* __restrict__ src, const int* __restrict__ dst,
    int* __restrict__ gcur, int* __restrict__ ebuck)
{
    __shared__ int hist[NBUCK];
    __shared__ int lcur[NBUCK];
    const int t = threadIdx.x;
    const int e0 = blockIdx.x * TILE_A;
    const int e1 = (e0 + TILE_A < NE) ? e0 + TILE_A : NE;

    for (int i = t; i < NBUCK; i += 256) hist[i] = 0;
    __syncthreads();
    for (int e = e0 + t; e < e1; e += 256)
        atomicAdd(&hist[dst[e] >> 8], 1);
    __syncthreads();
    for (int i = t; i < NBUCK; i += 256) {
        int hv = hist[i];
        lcur[i] = hv ? atomicAdd(&gcur[i], hv) : 0;
    }
    __syncthreads();
    for (int e = e0 + t; e < e1; e += 256) {
        int d = dst[e], s = src[e];
        int p = atomicAdd(&lcur[d >> 8], 1);
        ebuck[p] = (s << 8) | (d & 255);
    }
}

// ---------------- Pass B: per-bucket CSR scatter (LDS cursors) --------------
__global__ __launch_bounds__(256) void partitionB_kernel(
    const int* __restrict__ row_ptr, const int* __restrict__ ebuck,
    int* __restrict__ esrc)
{
    __shared__ int lcur[256];
    const int b = blockIdx.x;
    const int n0 = b << 8;
    const int n1 = (n0 + 256 < NN) ? n0 + 256 : NN;
    const int t = threadIdx.x;
    if (n0 + t < n1) lcur[t] = row_ptr[n0 + t];
    __syncthreads();
    const int r0 = row_ptr[n0], r1 = row_ptr[n1];
    for (int e = r0 + t; e < r1; e += 256) {
        int pk = ebuck[e];
        int p = atomicAdd(&lcur[pk & 255], 1);
        esrc[p] = pk >> 8;
    }
}

// ---------------- fused per-destination GAT gather -------------------------
template<int F, bool FINAL_LAYER>
__global__ __launch_bounds__(256) void gat_gather_kernel(
    const int* __restrict__ row_ptr, const int* __restrict__ esrc,
    const float* __restrict__ el, const float* __restrict__ er,
    const float* __restrict__ z, const float* __restrict__ bias,
    float* __restrict__ out)
{
    __shared__ float sw[4][64];
    __shared__ int   ssn[4][64];
    const int w = threadIdx.x >> 6, lane = threadIdx.x & 63;
    const int d = blockIdx.x * 4 + w;          // NN % 4 == 0
    const int r0 = row_ptr[d], r1 = row_ptr[d + 1];
    const int cnt = r1 - r0;
    const float erd = er[d];

    float accv = 0.f;
    float s = 0.f;

    if (cnt <= 64) {
        int sn = 0; float v = -INFINITY;
        if (lane < cnt) {
            sn = esrc[r0 + lane];
            v = el[sn] + erd;
            v = (v >= 0.f) ? v : SLOPE * v;
        }
        float m = v;
        #pragma unroll
        for (int off = 32; off >= 1; off >>= 1) m = fmaxf(m, __shfl_xor(m, off));
        float wv = (lane < cnt) ? __expf(v - m) : 0.f;
        s = wv;
        #pragma unroll
        for (int off = 32; off >= 1; off >>= 1) s += __shfl_xor(s, off);
        sw[w][lane] = wv; ssn[w][lane] = sn;   // wave-synchronous
        if (lane < F) {
            int j = 0;
            for (; j + 8 <= cnt; j += 8) {
                float acc0 = 0.f, acc1 = 0.f;
                #pragma unroll
                for (int q = 0; q < 8; q += 2) {
                    float wa = sw[w][j + q],     wb = sw[w][j + q + 1];
                    int   sa = ssn[w][j + q],    sb = ssn[w][j + q + 1];
                    acc0 += wa * z[(size_t)sa * F + lane];
                    acc1 += wb * z[(size_t)sb * F + lane];
                }
                accv += acc0 + acc1;
            }
            for (; j < cnt; ++j)
                accv += sw[w][j] * z[(size_t)ssn[w][j] * F + lane];
        }
    } else {
        float m = -INFINITY;
        for (int e = r0 + lane; e < r1; e += 64) {
            float v = el[esrc[e]] + erd;
            v = (v >= 0.f) ? v : SLOPE * v;
            m = fmaxf(m, v);
        }
        #pragma unroll
        for (int off = 32; off >= 1; off >>= 1) m = fmaxf(m, __shfl_xor(m, off));
        for (int base = r0; base < r1; base += 64) {
            int e = base + lane;
            float wv = 0.f; int sn = 0;
            if (e < r1) {
                sn = esrc[e];
                float v = el[sn] + erd;
                v = (v >= 0.f) ? v : SLOPE * v;
                wv = __expf(v - m);
            }
            sw[w][lane] = wv; ssn[w][lane] = sn;
            s += wv;
            int c = r1 - base; if (c > 64) c = 64;
            if (lane < F) {
                for (int j = 0; j < c; ++j)
                    accv += sw[w][j] * z[(size_t)ssn[w][j] * F + lane];
            }
        }
        #pragma unroll
        for (int off = 32; off >= 1; off >>= 1) s += __shfl_xor(s, off);
    }

    float res = (cnt > 0) ? (accv / s) : 0.f;

    if (!FINAL_LAYER) {
        if (lane < F) {
            float v = res + bias[lane];
            out[(size_t)d * F + lane] = (v > 0.f) ? v : 0.f;
        }
    } else {
        float v = (lane < F) ? res + bias[lane] : -INFINITY;
        float mx = v;
        #pragma unroll
        for (int off = 32; off >= 1; off >>= 1) mx = fmaxf(mx, __shfl_xor(mx, off));
        float ex = (lane < F) ? __expf(v - mx) : 0.f;
        float sm = ex;
        #pragma unroll
        for (int off = 32; off >= 1; off >>= 1) sm += __shfl_xor(sm, off);
        if (lane < F) out[(size_t)d * F + lane] = v - mx - __logf(sm);
    }
}

extern "C" void kernel_launch(void* const* d_in, const int* in_sizes, int n_in,
                              void* d_out, int out_size, void* d_ws, size_t ws_size,
                              hipStream_t stream) {
    const float* feat = (const float*)d_in[0];
    const int*   src  = (const int*)d_in[1];
    const int*   dst  = (const int*)d_in[2];
    const float* W1   = (const float*)d_in[3];
    const float* b1   = (const float*)d_in[4];
    const float* al1  = (const float*)d_in[5];
    const float* ar1  = (const float*)d_in[6];
    const float* W2   = (const float*)d_in[7];
    const float* b2   = (const float*)d_in[8];
    const float* al2  = (const float*)d_in[9];
    const float* ar2  = (const float*)d_in[10];
    float* out = (float*)d_out;

    float* ws    = (float*)d_ws;
    float* z1    = ws;                          // NN*64 (reused for z2)
    float* h     = z1 + (size_t)NN * HID;       // NN*64
    float* el1   = h + (size_t)NN * HID;
    float* er1   = el1 + NN;
    float* el2   = er1 + NN;
    float* er2   = el2 + NN;
    int*   deg   = (int*)(er2 + NN);            // NN
    int*   rowp  = deg + NN;                    // NN+1
    int*   bsum  = rowp + NN + 1;               // NB
    int*   bofs  = bsum + NB;                   // NB
    int*   gcur  = bofs + NB;                   // NBUCK
    int*   esrc  = gcur + NBUCK;                // NE
    int*   ebuck = (int*)h;                     // NE, dead before gather1 writes h
    float* z2    = z1;

    hipMemsetAsync(deg, 0, NN * sizeof(int), stream);

    // ---- layer-1 GEMM with fused dst-histogram ----
    gemm1_kernel<<<(NN + 63) / 64, 256, 0, stream>>>(feat, W1, al1, ar1, dst, deg, z1, el1, er1);

    // ---- CSR build ----
    scan_reduce_kernel<<<NB, 256, 0, stream>>>(deg, bsum);
    scan_top_kernel<<<1, 512, 0, stream>>>(bsum, bofs, rowp);
    scan_final_kernel<<<NB, 256, 0, stream>>>(deg, bofs, rowp, gcur);
    partitionA_kernel<<<NWG_A, 256, 0, stream>>>(src, dst, gcur, ebuck);
    partitionB_kernel<<<NBUCK, 256, 0, stream>>>(rowp, ebuck, esrc);

    // ---- layer 1 gather ----
    gat_gather_kernel<HID, false><<<NN / 4, 256, 0, stream>>>(rowp, esrc, el1, er1, z1, b1, h);

    // ---- layer 2 ----
    gemm2_kernel<<<NN / 4, 256, 0, stream>>>(h, W2, al2, ar2, z2, el2, er2);
    gat_gather_kernel<FOUT, true><<<NN / 4, 256, 0, stream>>>(rowp, esrc, el2, er2, z2, b2, out);
}